// Round 2
// baseline (1184.330 us; speedup 1.0000x reference)
//
#include <hip/hip_runtime.h>

#define NN 16384          // sequence length
#define NB 8              // batch
#define NC 16             // layer channels
#define NPOSTOT (NB * NN) // total positions = 131072

typedef float4 f4;

// ---------------- layer 0: causal conv 1->16, d=1, plus broadcast residual ----
__global__ __launch_bounds__(256) void layer0_k(
    const float* __restrict__ x,
    const float* __restrict__ W0, const float* __restrict__ b0,
    float* __restrict__ dst)
{
    const int p = blockIdx.x * 256 + threadIdx.x;     // position in [0, B*N)
    const int n = p & (NN - 1);
    const float xs = x[p] * (1.0f / 32768.0f);
    const float xm = (n >= 1) ? x[p - 1] * (1.0f / 32768.0f) : 0.0f;

    float v[NC];
#pragma unroll
    for (int c = 0; c < NC; ++c)
        v[c] = xs + fmaf(W0[c * 2], xm, fmaf(W0[c * 2 + 1], xs, b0[c]));

    f4* dv = (f4*)(dst + (size_t)p * NC);
#pragma unroll
    for (int i = 0; i < 4; ++i)
        dv[i] = make_float4(v[4 * i], v[4 * i + 1], v[4 * i + 2], v[4 * i + 3]);
}

// ---------------- gated residual layer, channel-split across wave pairs -------
// Block = 256 threads = 4 waves = 128 positions x 2 channel-halves.
// wave w: half = w&1 owns output channels [half*8, half*8+8); positions
// (w>>1)*64 + lane. z exchanged via LDS.
__global__ __launch_bounds__(256) void gated_k(
    const float* __restrict__ src, float* __restrict__ dst,
    const float* __restrict__ Wf, const float* __restrict__ bf,
    const float* __restrict__ Wg, const float* __restrict__ bg,
    const float* __restrict__ Wr, const float* __restrict__ br,
    int dil)
{
    __shared__ float zl[128 * 17];

    const int t = threadIdx.x;
    const int lane = t & 63;
    const int w = t >> 6;
    const int half = w & 1;
    const int pl = ((w >> 1) << 6) + lane;            // 0..127
    const int p = blockIdx.x * 128 + pl;
    const int n = p & (NN - 1);
    const float pad = (n >= dil) ? 1.0f : 0.0f;
    const int pp = (n >= dil) ? (p - dil) : p;

    float xc[NC], xp[NC];
    {
        const f4* a = (const f4*)(src + (size_t)p * NC);
        const f4* bq = (const f4*)(src + (size_t)pp * NC);
#pragma unroll
        for (int i = 0; i < 4; ++i) {
            f4 tt = a[i];
            xc[4 * i + 0] = tt.x; xc[4 * i + 1] = tt.y;
            xc[4 * i + 2] = tt.z; xc[4 * i + 3] = tt.w;
            f4 u = bq[i];
            xp[4 * i + 0] = u.x * pad; xp[4 * i + 1] = u.y * pad;
            xp[4 * i + 2] = u.z * pad; xp[4 * i + 3] = u.w * pad;
        }
    }

    const int ob = half * 8;
    float z[8];
#pragma unroll
    for (int i = 0; i < 8; ++i) {
        const int o = ob + i;
        float af0 = bf[o], af1 = 0.f, af2 = 0.f, af3 = 0.f;
        float ag0 = bg[o], ag1 = 0.f, ag2 = 0.f, ag3 = 0.f;
#pragma unroll
        for (int c = 0; c < 16; c += 2) {
            const int w0 = (o * 16 + c) * 2;
            af0 = fmaf(Wf[w0],     xp[c],     af0);
            af1 = fmaf(Wf[w0 + 1], xc[c],     af1);
            af2 = fmaf(Wf[w0 + 2], xp[c + 1], af2);
            af3 = fmaf(Wf[w0 + 3], xc[c + 1], af3);
            ag0 = fmaf(Wg[w0],     xp[c],     ag0);
            ag1 = fmaf(Wg[w0 + 1], xc[c],     ag1);
            ag2 = fmaf(Wg[w0 + 2], xp[c + 1], ag2);
            ag3 = fmaf(Wg[w0 + 3], xc[c + 1], ag3);
        }
        const float af = (af0 + af1) + (af2 + af3);
        const float ag = (ag0 + ag1) + (ag2 + ag3);
        // tanh(af) = 1 - 2/(exp(2*af)+1); sigmoid(ag) = 1/(1+exp(-ag))
        const float ef = __expf(2.0f * af);
        const float tf = 1.0f - 2.0f * __builtin_amdgcn_rcpf(ef + 1.0f);
        const float sg = __builtin_amdgcn_rcpf(1.0f + __expf(-ag));
        z[i] = tf * sg;
        zl[pl * 17 + o] = z[i];
    }
    __syncthreads();

    float zz[16];
    const int oo = 8 - ob;                            // other half's base
#pragma unroll
    for (int i = 0; i < 8; ++i) {
        zz[ob + i] = z[i];
        zz[oo + i] = zl[pl * 17 + oo + i];
    }

#pragma unroll
    for (int i = 0; i < 8; ++i) {
        const int o = ob + i;
        float a0 = br[o], a1 = 0.f, a2 = 0.f, a3 = 0.f;
#pragma unroll
        for (int c = 0; c < 16; c += 4) {
            a0 = fmaf(Wr[o * 16 + c],     zz[c],     a0);
            a1 = fmaf(Wr[o * 16 + c + 1], zz[c + 1], a1);
            a2 = fmaf(Wr[o * 16 + c + 2], zz[c + 2], a2);
            a3 = fmaf(Wr[o * 16 + c + 3], zz[c + 3], a3);
        }
        xc[o] += (a0 + a1) + (a2 + a3);               // residual on own channels
    }

    float* dp = dst + (size_t)p * NC + ob;
    *(f4*)(dp)     = make_float4(xc[ob],     xc[ob + 1], xc[ob + 2], xc[ob + 3]);
    *(f4*)(dp + 4) = make_float4(xc[ob + 4], xc[ob + 5], xc[ob + 6], xc[ob + 7]);
}

// ---------------- head: tile of 64 positions, 8 waves, logits computed once --
__global__ __launch_bounds__(512) void head_k(
    const float* __restrict__ fin, const float* __restrict__ x,
    const int* __restrict__ lengths,
    const float* __restrict__ Wa, const float* __restrict__ ba,
    const float* __restrict__ Wo, const float* __restrict__ bo,
    float* __restrict__ out)
{
    __shared__ float sk[64 * 17];
    __shared__ float ra[64 * 66];
    __shared__ float2 part[8 * 64];
    __shared__ float lsebuf[64];

    const int t = threadIdx.x;
    const int lane = t & 63;
    const int wave = t >> 6;
    const int p0 = blockIdx.x * 64;
    const int p = p0 + lane;
    const int b = p >> 14;
    const int n = p & (NN - 1);

    // Phase A: sk = relu(fin - xs) into LDS (first 4 waves, f4 loads)
    if (t < 256) {
        const int plc = t >> 2;                       // 0..63
        const int c4 = (t & 3) * 4;
        const int pq = p0 + plc;
        const float xs = x[pq] * (1.0f / 32768.0f);
        f4 v = *(const f4*)(fin + (size_t)pq * NC + c4);
        sk[plc * 17 + c4 + 0] = fmaxf(v.x - xs, 0.0f);
        sk[plc * 17 + c4 + 1] = fmaxf(v.y - xs, 0.0f);
        sk[plc * 17 + c4 + 2] = fmaxf(v.z - xs, 0.0f);
        sk[plc * 17 + c4 + 3] = fmaxf(v.w - xs, 0.0f);
    }
    __syncthreads();

    // Phase B: ra = relu(Wa @ sk + ba); wave w computes o in [w*8, w*8+8)
    {
        float s_[16];
#pragma unroll
        for (int c = 0; c < 16; ++c) s_[c] = sk[lane * 17 + c];
        const int obx = wave * 8;
#pragma unroll
        for (int i = 0; i < 8; ++i) {
            const int o = obx + i;
            float a0 = ba[o], a1 = 0.f, a2 = 0.f, a3 = 0.f;
#pragma unroll
            for (int c = 0; c < 16; c += 4) {
                a0 = fmaf(Wa[o * 16 + c],     s_[c],     a0);
                a1 = fmaf(Wa[o * 16 + c + 1], s_[c + 1], a1);
                a2 = fmaf(Wa[o * 16 + c + 2], s_[c + 2], a2);
                a3 = fmaf(Wa[o * 16 + c + 3], s_[c + 3], a3);
            }
            ra[lane * 66 + o] = fmaxf((a0 + a1) + (a2 + a3), 0.0f);
        }
    }
    __syncthreads();

    // Phase C: pull this position's ra row into registers
    float r_[64];
#pragma unroll
    for (int o = 0; o < 64; o += 2) {
        float2 v = *(const float2*)&ra[lane * 66 + o];
        r_[o] = v.x; r_[o + 1] = v.y;
    }

    // Phase D: this wave's 32 logits (Wo rows wave-uniform -> s_load)
    float l_[32];
    const int qb = wave * 32;
#pragma unroll 2
    for (int j = 0; j < 32; ++j) {
        const int q = qb + j;
        const float* wr = Wo + q * 64;
        float a0 = bo[q], a1 = 0.f, a2 = 0.f, a3 = 0.f;
#pragma unroll
        for (int o = 0; o < 64; o += 4) {
            a0 = fmaf(wr[o],     r_[o],     a0);
            a1 = fmaf(wr[o + 1], r_[o + 1], a1);
            a2 = fmaf(wr[o + 2], r_[o + 2], a2);
            a3 = fmaf(wr[o + 3], r_[o + 3], a3);
        }
        l_[j] = (a0 + a1) + (a2 + a3);
    }

    // Phase E: local online-LSE over this wave's 32 logits
    float m = l_[0];
#pragma unroll
    for (int j = 1; j < 32; ++j) m = fmaxf(m, l_[j]);
    float s = 0.f;
#pragma unroll
    for (int j = 0; j < 32; ++j) s += __expf(l_[j] - m);

    part[wave * 64 + lane] = make_float2(m, s);
    __syncthreads();

    // Phase F: combine 8 wave-partials per position (wave 0)
    if (wave == 0) {
        float2 c0 = part[lane];
        float mm = c0.x, ss = c0.y;
#pragma unroll
        for (int ww = 1; ww < 8; ++ww) {
            float2 d = part[ww * 64 + lane];
            const float nm = fmaxf(mm, d.x);
            ss = ss * __expf(mm - nm) + d.y * __expf(d.x - nm);
            mm = nm;
        }
        lsebuf[lane] = mm + __logf(ss);
    }
    __syncthreads();

    const float lse = lsebuf[lane];
    const bool valid = n < lengths[b];

    // Phase G: coalesced write (64 consecutive n per store)
    float* obp = out + (size_t)b * 256 * NN + n;
#pragma unroll
    for (int j = 0; j < 32; ++j)
        obp[(size_t)(qb + j) * NN] = valid ? (l_[j] - lse) : 0.0f;
}

extern "C" void kernel_launch(void* const* d_in, const int* in_sizes, int n_in,
                              void* d_out, int out_size, void* d_ws, size_t ws_size,
                              hipStream_t stream)
{
    const float* x       = (const float*)d_in[0];
    const int*   lengths = (const int*)d_in[1];
    const float* W0      = (const float*)d_in[2];
    const float* b0      = (const float*)d_in[3];
    const float* Wf      = (const float*)d_in[4];
    const float* bf      = (const float*)d_in[5];
    const float* Wg      = (const float*)d_in[6];
    const float* bg      = (const float*)d_in[7];
    const float* Wr      = (const float*)d_in[8];
    const float* br      = (const float*)d_in[9];
    const float* Wa      = (const float*)d_in[10];
    const float* ba      = (const float*)d_in[11];
    const float* Wo      = (const float*)d_in[12];
    const float* bo      = (const float*)d_in[13];
    float* out = (float*)d_out;

    float* buf0 = (float*)d_ws;                    // (B,N,16) fp32, 8.4 MB
    float* buf1 = buf0 + (size_t)NPOSTOT * NC;     // ping-pong partner

    layer0_k<<<dim3(NPOSTOT / 256), dim3(256), 0, stream>>>(x, W0, b0, buf0);

    int cur = 0;
    for (int i = 1; i < 30; ++i) {
        const int j = i - 1;
        const int dil = 1 << (i % 10);
        const float* s = cur ? buf1 : buf0;
        float* d       = cur ? buf0 : buf1;
        gated_k<<<dim3(NPOSTOT / 128), dim3(256), 0, stream>>>(
            s, d,
            Wf + (size_t)j * NC * NC * 2, bf + (size_t)j * NC,
            Wg + (size_t)j * NC * NC * 2, bg + (size_t)j * NC,
            Wr + (size_t)j * NC * NC,     br + (size_t)j * NC,
            dil);
        cur ^= 1;
    }

    const float* fin = cur ? buf1 : buf0;
    head_k<<<dim3(NPOSTOT / 64), dim3(512), 0, stream>>>(
        fin, x, lengths, Wa, ba, Wo, bo, out);
}

// Round 3
// 241.639 us; speedup vs baseline: 4.9012x; 4.9012x over previous
//
#include <hip/hip_runtime.h>
#include <hip/hip_bf16.h>

#define NN 16384          // sequence length
#define NB 8              // batch
#define NC 16             // layer channels
#define NPOSTOT (NB * NN) // total positions = 131072
#define NLAY 29           // gated layers

typedef float4 f4;
typedef short bf16x8 __attribute__((ext_vector_type(8)));
typedef float f32x4 __attribute__((ext_vector_type(4)));

// prepack element offsets (in shorts)
#define OFF_WF 0
#define OFF_WG (NLAY * 512)             // 14848
#define OFF_WR (2 * NLAY * 512)         // 29696
#define OFF_WA (3 * NLAY * 512)         // 44544
#define OFF_WO (3 * NLAY * 512 + 2048)  // 46592
#define PK_TOT (OFF_WO + 16384)         // 62976 shorts = 125952 B

static __device__ __forceinline__ short to_bf16(float f) {
    __hip_bfloat16 h = __float2bfloat16(f);   // RNE
    short s;
    __builtin_memcpy(&s, &h, 2);
    return s;
}

// ---------------- weight prepack into MFMA A-fragments (bf16) -----------------
// Conventions (slot-consistency: A and B packed with the same (h=lane>>4, j)->k
// bijection, so internal HW k-order is irrelevant):
//  conv (K=32):  k = h*8+j ; tap = k>>4, c = k&15           (B built from memory)
//  1x1  (K=32):  j<4 -> k = h*4+j (=channel), j>=4 -> zero  (B = conv output, lane-local)
//  Wa   (K=32):  k = h*8+j, real for k<16 (c=k), else zero  (B from memory)
//  Wo   (K=64):  half hf, k = hf*32 + (j>>2)*16 + h*4 + (j&3)  (B = Wa output, lane-local)
__global__ __launch_bounds__(256) void prepack_k(
    const float* __restrict__ Wf, const float* __restrict__ Wg,
    const float* __restrict__ Wr, const float* __restrict__ Wa,
    const float* __restrict__ Wo, short* __restrict__ pk)
{
    const int i = blockIdx.x * 256 + threadIdx.x;
    if (i >= PK_TOT) return;
    float val;
    if (i < OFF_WG) {                               // Wf frags
        const int j = i >> 9, r = i & 511, l = r >> 3, j8 = r & 7;
        const int o = l & 15, h = l >> 4;
        const int k = h * 8 + j8, tap = k >> 4, c = k & 15;
        val = Wf[((j * 16 + o) * 16 + c) * 2 + tap];
    } else if (i < OFF_WR) {                        // Wg frags
        const int i2 = i - OFF_WG;
        const int j = i2 >> 9, r = i2 & 511, l = r >> 3, j8 = r & 7;
        const int o = l & 15, h = l >> 4;
        const int k = h * 8 + j8, tap = k >> 4, c = k & 15;
        val = Wg[((j * 16 + o) * 16 + c) * 2 + tap];
    } else if (i < OFF_WA) {                        // Wr frags (half zero-padded)
        const int i2 = i - OFF_WR;
        const int j = i2 >> 9, r = i2 & 511, l = r >> 3, j8 = r & 7;
        const int o = l & 15, h = l >> 4;
        val = (j8 < 4) ? Wr[j * 256 + o * 16 + h * 4 + j8] : 0.0f;
    } else if (i < OFF_WO) {                        // Wa frags (4 m-tiles)
        const int i2 = i - OFF_WA;
        const int mt = i2 >> 9, r = i2 & 511, l = r >> 3, j8 = r & 7;
        const int og = mt * 16 + (l & 15), h = l >> 4;
        const int k = h * 8 + j8;
        val = (k < 16) ? Wa[og * 16 + k] : 0.0f;
    } else {                                        // Wo frags (16 q-tiles x 2 halves)
        const int i2 = i - OFF_WO;
        const int qt = i2 >> 10, hf = (i2 >> 9) & 1, r = i2 & 511;
        const int l = r >> 3, j8 = r & 7;
        const int q = qt * 16 + (l & 15), h = l >> 4;
        const int kg = hf * 32 + (j8 >> 2) * 16 + h * 4 + (j8 & 3);
        val = Wo[q * 64 + kg];
    }
    pk[i] = to_bf16(val);
}

// ---------------- layer 0: causal conv 1->16, d=1, plus broadcast residual ----
__global__ __launch_bounds__(256) void layer0_k(
    const float* __restrict__ x,
    const float* __restrict__ W0, const float* __restrict__ b0,
    float* __restrict__ dst)
{
    const int p = blockIdx.x * 256 + threadIdx.x;
    const int n = p & (NN - 1);
    const float xs = x[p] * (1.0f / 32768.0f);
    const float xm = (n >= 1) ? x[p - 1] * (1.0f / 32768.0f) : 0.0f;

    float v[NC];
#pragma unroll
    for (int c = 0; c < NC; ++c)
        v[c] = xs + fmaf(W0[c * 2], xm, fmaf(W0[c * 2 + 1], xs, b0[c]));

    f4* dv = (f4*)(dst + (size_t)p * NC);
#pragma unroll
    for (int i = 0; i < 4; ++i)
        dv[i] = make_float4(v[4 * i], v[4 * i + 1], v[4 * i + 2], v[4 * i + 3]);
}

// ---------------- gated residual layer via MFMA: wave = 16 pos x 16 ch --------
__global__ __launch_bounds__(256) void gatedm_k(
    const float* __restrict__ src, float* __restrict__ dst,
    const short* __restrict__ pkf, const short* __restrict__ pkg,
    const short* __restrict__ pkr,
    const float* __restrict__ bf, const float* __restrict__ bg,
    const float* __restrict__ br, int dil)
{
    const int t = threadIdx.x;
    const int lane = t & 63;
    const int wv = t >> 6;
    const int pos = blockIdx.x * 64 + wv * 16 + (lane & 15);
    const int h = lane >> 4;
    const int n = pos & (NN - 1);

    // B fragment (shared by f and g convs): x_tap[pos][c0..c0+7]
    const int tap = h >> 1;
    const int c0 = (h & 1) * 8;
    const bool live = tap || (n >= dil);
    const int q = (tap || n < dil) ? pos : pos - dil;
    const float sc = live ? 1.0f : 0.0f;
    const float* bp = src + (size_t)q * NC + c0;
    const f4 v0 = *(const f4*)bp;
    const f4 v1 = *(const f4*)(bp + 4);
    bf16x8 bx;
    bx[0] = to_bf16(v0.x * sc); bx[1] = to_bf16(v0.y * sc);
    bx[2] = to_bf16(v0.z * sc); bx[3] = to_bf16(v0.w * sc);
    bx[4] = to_bf16(v1.x * sc); bx[5] = to_bf16(v1.y * sc);
    bx[6] = to_bf16(v1.z * sc); bx[7] = to_bf16(v1.w * sc);

    // A fragments + bias C-init
    const bf16x8 af = *(const bf16x8*)(pkf + lane * 8);
    const bf16x8 ag = *(const bf16x8*)(pkg + lane * 8);
    const f4 bfv = *(const f4*)(bf + h * 4);
    const f4 bgv = *(const f4*)(bg + h * 4);
    f32x4 cf = {bfv.x, bfv.y, bfv.z, bfv.w};
    f32x4 cg = {bgv.x, bgv.y, bgv.z, bgv.w};

    const f32x4 fp = __builtin_amdgcn_mfma_f32_16x16x32_bf16(af, bx, cf, 0, 0, 0);
    const f32x4 gp = __builtin_amdgcn_mfma_f32_16x16x32_bf16(ag, bx, cg, 0, 0, 0);

    // activations; z lands exactly in the 1x1's B-fragment slots (j<4)
    bf16x8 bz;
#pragma unroll
    for (int r = 0; r < 4; ++r) {
        const float ef = __expf(2.0f * fp[r]);
        const float tf = 1.0f - 2.0f * __builtin_amdgcn_rcpf(ef + 1.0f);
        const float sg = __builtin_amdgcn_rcpf(1.0f + __expf(-gp[r]));
        bz[r] = to_bf16(tf * sg);
        bz[r + 4] = 0;
    }

    const bf16x8 ar = *(const bf16x8*)(pkr + lane * 8);
    const f4 brv = *(const f4*)(br + h * 4);
    f32x4 cr = {brv.x, brv.y, brv.z, brv.w};
    const f32x4 o = __builtin_amdgcn_mfma_f32_16x16x32_bf16(ar, bz, cr, 0, 0, 0);

    // residual add; lane writes (pos, ch=h*4..h*4+3) -> 1KB contiguous per wave
    const f4 old = *(const f4*)(src + (size_t)pos * NC + h * 4);
    *(f4*)(dst + (size_t)pos * NC + h * 4) =
        make_float4(old.x + o[0], old.y + o[1], old.z + o[2], old.w + o[3]);
}

// ---------------- head via MFMA: skip->64->256->log_softmax, no LDS ----------
__global__ __launch_bounds__(256) void headm_k(
    const float* __restrict__ fin, const float* __restrict__ x,
    const int* __restrict__ lengths,
    const short* __restrict__ pka, const float* __restrict__ ba,
    const short* __restrict__ pko, const float* __restrict__ bo,
    float* __restrict__ out)
{
    const int t = threadIdx.x;
    const int lane = t & 63;
    const int wv = t >> 6;
    const int pos = blockIdx.x * 64 + wv * 16 + (lane & 15);
    const int h = lane >> 4;
    const int b = pos >> 14;
    const int n = pos & (NN - 1);

    // B fragment for Wa: sk = relu(fin - xs), channels k=h*8+j (real for h<2)
    bf16x8 bs;
    if (h < 2) {
        const float xs = x[pos] * (1.0f / 32768.0f);
        const float* fp = fin + (size_t)pos * NC + h * 8;
        const f4 v0 = *(const f4*)fp;
        const f4 v1 = *(const f4*)(fp + 4);
        bs[0] = to_bf16(fmaxf(v0.x - xs, 0.0f)); bs[1] = to_bf16(fmaxf(v0.y - xs, 0.0f));
        bs[2] = to_bf16(fmaxf(v0.z - xs, 0.0f)); bs[3] = to_bf16(fmaxf(v0.w - xs, 0.0f));
        bs[4] = to_bf16(fmaxf(v1.x - xs, 0.0f)); bs[5] = to_bf16(fmaxf(v1.y - xs, 0.0f));
        bs[6] = to_bf16(fmaxf(v1.z - xs, 0.0f)); bs[7] = to_bf16(fmaxf(v1.w - xs, 0.0f));
    } else {
#pragma unroll
        for (int j = 0; j < 8; ++j) bs[j] = 0;
    }

    // Wa GEMM: ra[mt*4+r] = relu(...), 16 values/lane, lane-local for Wo B-frags
    float ra[16];
#pragma unroll
    for (int mt = 0; mt < 4; ++mt) {
        const bf16x8 aa = *(const bf16x8*)(pka + (mt * 64 + lane) * 8);
        const f4 bav = *(const f4*)(ba + mt * 16 + h * 4);
        f32x4 c = {bav.x, bav.y, bav.z, bav.w};
        c = __builtin_amdgcn_mfma_f32_16x16x32_bf16(aa, bs, c, 0, 0, 0);
#pragma unroll
        for (int r = 0; r < 4; ++r) ra[mt * 4 + r] = fmaxf(c[r], 0.0f);
    }
    bf16x8 blo, bhi;
#pragma unroll
    for (int j = 0; j < 8; ++j) { blo[j] = to_bf16(ra[j]); bhi[j] = to_bf16(ra[8 + j]); }

    // Wo GEMM: 16 q-tiles x (2 MFMA, K=64); logits kept in VGPRs
    float lg[64];
#pragma unroll
    for (int qt = 0; qt < 16; ++qt) {
        const bf16x8 a0 = *(const bf16x8*)(pko + ((qt * 2 + 0) * 64 + lane) * 8);
        const bf16x8 a1 = *(const bf16x8*)(pko + ((qt * 2 + 1) * 64 + lane) * 8);
        const f4 bov = *(const f4*)(bo + qt * 16 + h * 4);
        f32x4 c = {bov.x, bov.y, bov.z, bov.w};
        c = __builtin_amdgcn_mfma_f32_16x16x32_bf16(a0, blo, c, 0, 0, 0);
        c = __builtin_amdgcn_mfma_f32_16x16x32_bf16(a1, bhi, c, 0, 0, 0);
#pragma unroll
        for (int r = 0; r < 4; ++r) lg[qt * 4 + r] = c[r];
    }

    // LSE: 256 logits/position live on lanes {i, i+16, i+32, i+48}
    float m = lg[0];
#pragma unroll
    for (int j = 1; j < 64; ++j) m = fmaxf(m, lg[j]);
    m = fmaxf(m, __shfl_xor(m, 16, 64));
    m = fmaxf(m, __shfl_xor(m, 32, 64));
    float s = 0.0f;
#pragma unroll
    for (int j = 0; j < 64; ++j) s += __expf(lg[j] - m);
    s += __shfl_xor(s, 16, 64);
    s += __shfl_xor(s, 32, 64);
    const float lse = m + __logf(s);
    const bool valid = n < lengths[b];

    // write: q = qt*16 + h*4 + r at out[b][q][n]
    float* ob = out + (size_t)b * 256 * NN + n;
#pragma unroll
    for (int qt = 0; qt < 16; ++qt)
#pragma unroll
        for (int r = 0; r < 4; ++r)
            ob[(size_t)(qt * 16 + h * 4 + r) * NN] = valid ? (lg[qt * 4 + r] - lse) : 0.0f;
}

extern "C" void kernel_launch(void* const* d_in, const int* in_sizes, int n_in,
                              void* d_out, int out_size, void* d_ws, size_t ws_size,
                              hipStream_t stream)
{
    const float* x       = (const float*)d_in[0];
    const int*   lengths = (const int*)d_in[1];
    const float* W0      = (const float*)d_in[2];
    const float* b0      = (const float*)d_in[3];
    const float* Wf      = (const float*)d_in[4];
    const float* bf      = (const float*)d_in[5];
    const float* Wg      = (const float*)d_in[6];
    const float* bg      = (const float*)d_in[7];
    const float* Wr      = (const float*)d_in[8];
    const float* br      = (const float*)d_in[9];
    const float* Wa      = (const float*)d_in[10];
    const float* ba      = (const float*)d_in[11];
    const float* Wo      = (const float*)d_in[12];
    const float* bo      = (const float*)d_in[13];
    float* out = (float*)d_out;

    float* buf0 = (float*)d_ws;                    // (B,N,16) fp32, 8.4 MB
    float* buf1 = buf0 + (size_t)NPOSTOT * NC;     // ping-pong partner
    short* pk   = (short*)(buf1 + (size_t)NPOSTOT * NC);  // packed weight frags

    prepack_k<<<dim3((PK_TOT + 255) / 256), dim3(256), 0, stream>>>(
        Wf, Wg, Wr, Wa, Wo, pk);
    layer0_k<<<dim3(NPOSTOT / 256), dim3(256), 0, stream>>>(x, W0, b0, buf0);

    int cur = 0;
    for (int i = 1; i < 30; ++i) {
        const int j = i - 1;
        const int dil = 1 << (i % 10);
        const float* s = cur ? buf1 : buf0;
        float* d       = cur ? buf0 : buf1;
        gatedm_k<<<dim3(NPOSTOT / 64), dim3(256), 0, stream>>>(
            s, d,
            pk + OFF_WF + (size_t)j * 512,
            pk + OFF_WG + (size_t)j * 512,
            pk + OFF_WR + (size_t)j * 512,
            bf + (size_t)j * NC, bg + (size_t)j * NC, br + (size_t)j * NC,
            dil);
        cur ^= 1;
    }

    const float* fin = cur ? buf1 : buf0;
    headm_k<<<dim3(NPOSTOT / 64), dim3(256), 0, stream>>>(
        fin, x, lengths, pk + OFF_WA, ba, pk + OFF_WO, bo, out);
}

// Round 4
// 183.235 us; speedup vs baseline: 6.4635x; 1.3187x over previous
//
#include <hip/hip_runtime.h>
#include <hip/hip_bf16.h>

#define NN 16384          // sequence length
#define NB 8              // batch
#define NC 16             // layer channels
#define NPOSTOT (NB * NN) // total positions = 131072
#define NLAY 29           // gated layers

typedef float4 f4;
typedef short bf16x8 __attribute__((ext_vector_type(8)));
typedef float f32x4 __attribute__((ext_vector_type(4)));

// prepack element offsets (in shorts)
#define OFF_WF 0
#define OFF_WG (NLAY * 512)             // 14848
#define OFF_WR (2 * NLAY * 512)         // 29696
#define OFF_WA (3 * NLAY * 512)         // 44544
#define OFF_WO (3 * NLAY * 512 + 2048)  // 46592
#define PK_TOT (OFF_WO + 16384)         // 62976 shorts = 125952 B

static __device__ __forceinline__ short to_bf16(float f) {
    __hip_bfloat16 h = __float2bfloat16(f);   // RNE
    short s;
    __builtin_memcpy(&s, &h, 2);
    return s;
}
static __device__ __forceinline__ float from_bf16(short s) {
    unsigned int u = ((unsigned int)(unsigned short)s) << 16;
    float f;
    __builtin_memcpy(&f, &u, 4);
    return f;
}

// ---------------- weight prepack into MFMA A-fragments (bf16) -----------------
// Slot-consistency: A and B packed with the same (h=lane>>4, j)->k bijection.
//  conv (K=32):  k = h*8+j ; tap = k>>4, c = k&15           (B from memory)
//  1x1  (K=32):  j<4 -> k = h*4+j (=channel), j>=4 -> zero  (B = conv output)
//  Wa   (K=32):  k = h*8+j, real for k<16 (c=k), else zero  (B from memory)
//  Wo   (K=64):  half hf, k = hf*32 + (j>>2)*16 + h*4 + (j&3)  (B = Wa output)
__global__ __launch_bounds__(256) void prepack_k(
    const float* __restrict__ Wf, const float* __restrict__ Wg,
    const float* __restrict__ Wr, const float* __restrict__ Wa,
    const float* __restrict__ Wo, short* __restrict__ pk)
{
    const int i = blockIdx.x * 256 + threadIdx.x;
    if (i >= PK_TOT) return;
    float val;
    if (i < OFF_WG) {                               // Wf frags
        const int j = i >> 9, r = i & 511, l = r >> 3, j8 = r & 7;
        const int o = l & 15, h = l >> 4;
        const int k = h * 8 + j8, tap = k >> 4, c = k & 15;
        val = Wf[((j * 16 + o) * 16 + c) * 2 + tap];
    } else if (i < OFF_WR) {                        // Wg frags
        const int i2 = i - OFF_WG;
        const int j = i2 >> 9, r = i2 & 511, l = r >> 3, j8 = r & 7;
        const int o = l & 15, h = l >> 4;
        const int k = h * 8 + j8, tap = k >> 4, c = k & 15;
        val = Wg[((j * 16 + o) * 16 + c) * 2 + tap];
    } else if (i < OFF_WA) {                        // Wr frags (half zero-padded)
        const int i2 = i - OFF_WR;
        const int j = i2 >> 9, r = i2 & 511, l = r >> 3, j8 = r & 7;
        const int o = l & 15, h = l >> 4;
        val = (j8 < 4) ? Wr[j * 256 + o * 16 + h * 4 + j8] : 0.0f;
    } else if (i < OFF_WO) {                        // Wa frags (4 m-tiles)
        const int i2 = i - OFF_WA;
        const int mt = i2 >> 9, r = i2 & 511, l = r >> 3, j8 = r & 7;
        const int og = mt * 16 + (l & 15), h = l >> 4;
        const int k = h * 8 + j8;
        val = (k < 16) ? Wa[og * 16 + k] : 0.0f;
    } else {                                        // Wo frags (16 q-tiles x 2 halves)
        const int i2 = i - OFF_WO;
        const int qt = i2 >> 10, hf = (i2 >> 9) & 1, r = i2 & 511;
        const int l = r >> 3, j8 = r & 7;
        const int q = qt * 16 + (l & 15), h = l >> 4;
        const int kg = hf * 32 + (j8 >> 2) * 16 + h * 4 + (j8 & 3);
        val = Wo[q * 64 + kg];
    }
    pk[i] = to_bf16(val);
}

// ---------------- gated MFMA core (shared by both layer kernels) --------------
static __device__ __forceinline__ f32x4 gated_core(
    bf16x8 bx, const short* pkf, const short* pkg, const short* pkr,
    const float* bfv_, const float* bgv_, const float* brv_,
    int lane, int h)
{
    const bf16x8 af = *(const bf16x8*)(pkf + lane * 8);
    const bf16x8 ag = *(const bf16x8*)(pkg + lane * 8);
    const f4 bfv = *(const f4*)(bfv_ + h * 4);
    const f4 bgv = *(const f4*)(bgv_ + h * 4);
    f32x4 cf = {bfv.x, bfv.y, bfv.z, bfv.w};
    f32x4 cg = {bgv.x, bgv.y, bgv.z, bgv.w};

    const f32x4 fp = __builtin_amdgcn_mfma_f32_16x16x32_bf16(af, bx, cf, 0, 0, 0);
    const f32x4 gp = __builtin_amdgcn_mfma_f32_16x16x32_bf16(ag, bx, cg, 0, 0, 0);

    bf16x8 bz;
#pragma unroll
    for (int r = 0; r < 4; ++r) {
        const float ef = __expf(2.0f * fp[r]);
        const float tf = 1.0f - 2.0f * __builtin_amdgcn_rcpf(ef + 1.0f);
        const float sg = __builtin_amdgcn_rcpf(1.0f + __expf(-gp[r]));
        bz[r] = to_bf16(tf * sg);
        bz[r + 4] = 0;
    }

    const bf16x8 ar = *(const bf16x8*)(pkr + lane * 8);
    const f4 brv = *(const f4*)(brv_ + h * 4);
    f32x4 cr = {brv.x, brv.y, brv.z, brv.w};
    return __builtin_amdgcn_mfma_f32_16x16x32_bf16(ar, bz, cr, 0, 0, 0);
}

// ---------------- fused layer0 + gated layer 1 (dil=2), writes bf16 stream ----
__global__ __launch_bounds__(256) void gated1_k(
    const float* __restrict__ x,
    const float* __restrict__ W0, const float* __restrict__ b0,
    short* __restrict__ dst,
    const short* __restrict__ pkf, const short* __restrict__ pkg,
    const short* __restrict__ pkr,
    const float* __restrict__ bf1, const float* __restrict__ bg1,
    const float* __restrict__ br1)
{
    const int t = threadIdx.x;
    const int lane = t & 63;
    const int wv = t >> 6;
    const int pos = blockIdx.x * 64 + wv * 16 + (lane & 15);
    const int h = lane >> 4;
    const int n = pos & (NN - 1);
    const int dil = 2;

    const int tap = h >> 1;
    const int c0 = (h & 1) * 8;
    const bool live = tap || (n >= dil);
    const int q = (tap || n < dil) ? pos : pos - dil;

    // inp1 at position q, channels c0..c0+7, computed from x (layer0 fused)
    bf16x8 bx;
    if (live) {
        const int nq = q & (NN - 1);
        const float xs_q = x[q] * (1.0f / 32768.0f);
        const float xm_q = (nq >= 1) ? x[q - 1] * (1.0f / 32768.0f) : 0.0f;
#pragma unroll
        for (int j = 0; j < 8; ++j) {
            const int c = c0 + j;
            bx[j] = to_bf16(xs_q + fmaf(W0[c * 2], xm_q, fmaf(W0[c * 2 + 1], xs_q, b0[c])));
        }
    } else {
#pragma unroll
        for (int j = 0; j < 8; ++j) bx[j] = 0;
    }

    const f32x4 o = gated_core(bx, pkf, pkg, pkr, bf1, bg1, br1, lane, h);

    // residual: recompute inp1 at pos, channels h*4..h*4+3
    const float xs_p = x[pos] * (1.0f / 32768.0f);
    const float xm_p = (n >= 1) ? x[pos - 1] * (1.0f / 32768.0f) : 0.0f;
    short4 w;
    {
        float v[4];
#pragma unroll
        for (int r = 0; r < 4; ++r) {
            const int c = h * 4 + r;
            v[r] = xs_p + fmaf(W0[c * 2], xm_p, fmaf(W0[c * 2 + 1], xs_p, b0[c])) + o[r];
        }
        w = make_short4(to_bf16(v[0]), to_bf16(v[1]), to_bf16(v[2]), to_bf16(v[3]));
    }
    *(short4*)(dst + (size_t)pos * NC + h * 4) = w;
}

// ---------------- gated residual layer via MFMA on bf16 stream ----------------
__global__ __launch_bounds__(256) void gatedm_k(
    const short* __restrict__ src, short* __restrict__ dst,
    const short* __restrict__ pkf, const short* __restrict__ pkg,
    const short* __restrict__ pkr,
    const float* __restrict__ bf, const float* __restrict__ bg,
    const float* __restrict__ br, int dil)
{
    const int t = threadIdx.x;
    const int lane = t & 63;
    const int wv = t >> 6;
    const int pos = blockIdx.x * 64 + wv * 16 + (lane & 15);
    const int h = lane >> 4;
    const int n = pos & (NN - 1);

    const int tap = h >> 1;
    const int c0 = (h & 1) * 8;
    const bool live = tap || (n >= dil);
    const int q = (tap || n < dil) ? pos : pos - dil;

    bf16x8 bx;
    if (live) {
        bx = *(const bf16x8*)(src + (size_t)q * NC + c0);
    } else {
#pragma unroll
        for (int j = 0; j < 8; ++j) bx[j] = 0;
    }

    const f32x4 o = gated_core(bx, pkf, pkg, pkr, bf, bg, br, lane, h);

    // residual add in fp32, store bf16
    const short4 oldw = *(const short4*)(src + (size_t)pos * NC + h * 4);
    short4 w = make_short4(to_bf16(from_bf16(oldw.x) + o[0]),
                           to_bf16(from_bf16(oldw.y) + o[1]),
                           to_bf16(from_bf16(oldw.z) + o[2]),
                           to_bf16(from_bf16(oldw.w) + o[3]));
    *(short4*)(dst + (size_t)pos * NC + h * 4) = w;
}

// ---------------- head via MFMA: skip->64->256->log_softmax, no LDS ----------
__global__ __launch_bounds__(256) void headm_k(
    const short* __restrict__ fin, const float* __restrict__ x,
    const int* __restrict__ lengths,
    const short* __restrict__ pka, const float* __restrict__ ba,
    const short* __restrict__ pko, const float* __restrict__ bo,
    float* __restrict__ out)
{
    const int t = threadIdx.x;
    const int lane = t & 63;
    const int wv = t >> 6;
    const int pos = blockIdx.x * 64 + wv * 16 + (lane & 15);
    const int h = lane >> 4;
    const int b = pos >> 14;
    const int n = pos & (NN - 1);

    // B fragment for Wa: sk = relu(fin - xs), channels k=h*8+j (real for h<2)
    bf16x8 bs;
    if (h < 2) {
        const float xs = x[pos] * (1.0f / 32768.0f);
        const bf16x8 v = *(const bf16x8*)(fin + (size_t)pos * NC + h * 8);
#pragma unroll
        for (int j = 0; j < 8; ++j)
            bs[j] = to_bf16(fmaxf(from_bf16(v[j]) - xs, 0.0f));
    } else {
#pragma unroll
        for (int j = 0; j < 8; ++j) bs[j] = 0;
    }

    // Wa GEMM: ra = relu(...), 16 values/lane, lane-local for Wo B-frags
    float ra[16];
#pragma unroll
    for (int mt = 0; mt < 4; ++mt) {
        const bf16x8 aa = *(const bf16x8*)(pka + (mt * 64 + lane) * 8);
        const f4 bav = *(const f4*)(ba + mt * 16 + h * 4);
        f32x4 c = {bav.x, bav.y, bav.z, bav.w};
        c = __builtin_amdgcn_mfma_f32_16x16x32_bf16(aa, bs, c, 0, 0, 0);
#pragma unroll
        for (int r = 0; r < 4; ++r) ra[mt * 4 + r] = fmaxf(c[r], 0.0f);
    }
    bf16x8 blo, bhi;
#pragma unroll
    for (int j = 0; j < 8; ++j) { blo[j] = to_bf16(ra[j]); bhi[j] = to_bf16(ra[8 + j]); }

    // Wo GEMM: 16 q-tiles x (2 MFMA, K=64); logits kept in VGPRs
    float lg[64];
#pragma unroll
    for (int qt = 0; qt < 16; ++qt) {
        const bf16x8 a0 = *(const bf16x8*)(pko + ((qt * 2 + 0) * 64 + lane) * 8);
        const bf16x8 a1 = *(const bf16x8*)(pko + ((qt * 2 + 1) * 64 + lane) * 8);
        const f4 bov = *(const f4*)(bo + qt * 16 + h * 4);
        f32x4 c = {bov.x, bov.y, bov.z, bov.w};
        c = __builtin_amdgcn_mfma_f32_16x16x32_bf16(a0, blo, c, 0, 0, 0);
        c = __builtin_amdgcn_mfma_f32_16x16x32_bf16(a1, bhi, c, 0, 0, 0);
#pragma unroll
        for (int r = 0; r < 4; ++r) lg[qt * 4 + r] = c[r];
    }

    // LSE: 256 logits/position live on lanes {i, i+16, i+32, i+48}
    float m = lg[0];
#pragma unroll
    for (int j = 1; j < 64; ++j) m = fmaxf(m, lg[j]);
    m = fmaxf(m, __shfl_xor(m, 16, 64));
    m = fmaxf(m, __shfl_xor(m, 32, 64));
    float s = 0.0f;
#pragma unroll
    for (int j = 0; j < 64; ++j) s += __expf(lg[j] - m);
    s += __shfl_xor(s, 16, 64);
    s += __shfl_xor(s, 32, 64);
    const float lse = m + __logf(s);
    const bool valid = n < lengths[b];

    // write: q = qt*16 + h*4 + r at out[b][q][n]
    float* ob = out + (size_t)b * 256 * NN + n;
#pragma unroll
    for (int qt = 0; qt < 16; ++qt)
#pragma unroll
        for (int r = 0; r < 4; ++r)
            ob[(size_t)(qt * 16 + h * 4 + r) * NN] = valid ? (lg[qt * 4 + r] - lse) : 0.0f;
}

extern "C" void kernel_launch(void* const* d_in, const int* in_sizes, int n_in,
                              void* d_out, int out_size, void* d_ws, size_t ws_size,
                              hipStream_t stream)
{
    const float* x       = (const float*)d_in[0];
    const int*   lengths = (const int*)d_in[1];
    const float* W0      = (const float*)d_in[2];
    const float* b0      = (const float*)d_in[3];
    const float* Wf      = (const float*)d_in[4];
    const float* bf      = (const float*)d_in[5];
    const float* Wg      = (const float*)d_in[6];
    const float* bg      = (const float*)d_in[7];
    const float* Wr      = (const float*)d_in[8];
    const float* br      = (const float*)d_in[9];
    const float* Wa      = (const float*)d_in[10];
    const float* ba      = (const float*)d_in[11];
    const float* Wo      = (const float*)d_in[12];
    const float* bo      = (const float*)d_in[13];
    float* out = (float*)d_out;

    short* bufA = (short*)d_ws;                         // (B,N,16) bf16, 4.2 MB
    short* bufB = bufA + (size_t)NPOSTOT * NC;          // ping-pong partner
    short* pk   = bufB + (size_t)NPOSTOT * NC;          // packed weight frags

    prepack_k<<<dim3((PK_TOT + 255) / 256), dim3(256), 0, stream>>>(
        Wf, Wg, Wr, Wa, Wo, pk);

    // fused layer0 + gated layer 1 -> bufA
    gated1_k<<<dim3(NPOSTOT / 64), dim3(256), 0, stream>>>(
        x, W0, b0, bufA,
        pk + OFF_WF, pk + OFF_WG, pk + OFF_WR,
        bf, bg, br);

    int cur = 0;  // current = bufA
    for (int i = 2; i < 30; ++i) {
        const int j = i - 1;
        const int dil = 1 << (i % 10);
        const short* s = cur ? bufB : bufA;
        short* d       = cur ? bufA : bufB;
        gatedm_k<<<dim3(NPOSTOT / 64), dim3(256), 0, stream>>>(
            s, d,
            pk + OFF_WF + (size_t)j * 512,
            pk + OFF_WG + (size_t)j * 512,
            pk + OFF_WR + (size_t)j * 512,
            bf + (size_t)j * NC, bg + (size_t)j * NC, br + (size_t)j * NC,
            dil);
        cur ^= 1;
    }

    const short* fin = cur ? bufB : bufA;
    headm_k<<<dim3(NPOSTOT / 64), dim3(256), 0, stream>>>(
        fin, x, lengths, pk + OFF_WA, ba, pk + OFF_WO, bo, out);
}

// Round 5
// 174.064 us; speedup vs baseline: 6.8040x; 1.0527x over previous
//
#include <hip/hip_runtime.h>
#include <hip/hip_bf16.h>

#define NN 16384          // sequence length
#define NB 8              // batch
#define NC 16             // layer channels
#define NPOSTOT (NB * NN) // total positions = 131072
#define NLAY 29           // gated layers

typedef float4 f4;
typedef short bf16x8 __attribute__((ext_vector_type(8)));
typedef float f32x4 __attribute__((ext_vector_type(4)));

// prepack element offsets (in shorts)
#define OFF_WF 0
#define OFF_WG (NLAY * 512)             // 14848
#define OFF_WR (2 * NLAY * 512)         // 29696
#define OFF_WA (3 * NLAY * 512)         // 44544
#define OFF_WO (3 * NLAY * 512 + 2048)  // 46592
#define PK_TOT (OFF_WO + 16384)         // 62976 shorts = 125952 B

static __device__ __forceinline__ short to_bf16(float f) {
    __hip_bfloat16 h = __float2bfloat16(f);   // RNE
    short s;
    __builtin_memcpy(&s, &h, 2);
    return s;
}
static __device__ __forceinline__ float from_bf16(short s) {
    unsigned int u = ((unsigned int)(unsigned short)s) << 16;
    float f;
    __builtin_memcpy(&f, &u, 4);
    return f;
}

// ---------------- weight prepack into MFMA A-fragments (bf16) -----------------
// Slot-consistency: A and B packed with the same (h=lane>>4, j)->k bijection.
//  conv (K=32):  k = h*8+j ; tap = k>>4, c = k&15           (B from memory)
//  1x1  (K=32):  j<4 -> k = h*4+j (=channel), j>=4 -> zero  (B = conv output)
//  Wa   (K=32):  k = h*8+j, real for k<16 (c=k), else zero  (B from memory)
//  Wo   (K=64):  half hf, k = hf*32 + (j>>2)*16 + h*4 + (j&3)  (B = Wa output)
__global__ __launch_bounds__(256) void prepack_k(
    const float* __restrict__ Wf, const float* __restrict__ Wg,
    const float* __restrict__ Wr, const float* __restrict__ Wa,
    const float* __restrict__ Wo, short* __restrict__ pk)
{
    const int i = blockIdx.x * 256 + threadIdx.x;
    if (i >= PK_TOT) return;
    float val;
    if (i < OFF_WG) {                               // Wf frags
        const int j = i >> 9, r = i & 511, l = r >> 3, j8 = r & 7;
        const int o = l & 15, h = l >> 4;
        const int k = h * 8 + j8, tap = k >> 4, c = k & 15;
        val = Wf[((j * 16 + o) * 16 + c) * 2 + tap];
    } else if (i < OFF_WA) {
        const int i2 = i - OFF_WG;
        if (i2 < NLAY * 512) {                      // Wg frags
            const int j = i2 >> 9, r = i2 & 511, l = r >> 3, j8 = r & 7;
            const int o = l & 15, h = l >> 4;
            const int k = h * 8 + j8, tap = k >> 4, c = k & 15;
            val = Wg[((j * 16 + o) * 16 + c) * 2 + tap];
        } else {                                    // Wr frags (half zero-padded)
            const int i3 = i2 - NLAY * 512;
            const int j = i3 >> 9, r = i3 & 511, l = r >> 3, j8 = r & 7;
            const int o = l & 15, h = l >> 4;
            val = (j8 < 4) ? Wr[j * 256 + o * 16 + h * 4 + j8] : 0.0f;
        }
    } else if (i < OFF_WO) {                        // Wa frags (4 m-tiles)
        const int i2 = i - OFF_WA;
        const int mt = i2 >> 9, r = i2 & 511, l = r >> 3, j8 = r & 7;
        const int og = mt * 16 + (l & 15), h = l >> 4;
        const int k = h * 8 + j8;
        val = (k < 16) ? Wa[og * 16 + k] : 0.0f;
    } else {                                        // Wo frags (16 q-tiles x 2 halves)
        const int i2 = i - OFF_WO;
        const int qt = i2 >> 10, hf = (i2 >> 9) & 1, r = i2 & 511;
        const int l = r >> 3, j8 = r & 7;
        const int q = qt * 16 + (l & 15), h = l >> 4;
        const int kg = hf * 32 + (j8 >> 2) * 16 + h * 4 + (j8 & 3);
        val = Wo[q * 64 + kg];
    }
    pk[i] = to_bf16(val);
}

// ---------------- gated MFMA core with preloaded fragments --------------------
static __device__ __forceinline__ f32x4 gated_core2(
    bf16x8 bx, bf16x8 af, bf16x8 ag, bf16x8 ar,
    f32x4 cf, f32x4 cg, f32x4 cr)
{
    const f32x4 fp = __builtin_amdgcn_mfma_f32_16x16x32_bf16(af, bx, cf, 0, 0, 0);
    const f32x4 gp = __builtin_amdgcn_mfma_f32_16x16x32_bf16(ag, bx, cg, 0, 0, 0);

    bf16x8 bz;
#pragma unroll
    for (int r = 0; r < 4; ++r) {
        const float ef = __expf(2.0f * fp[r]);
        const float tf = 1.0f - 2.0f * __builtin_amdgcn_rcpf(ef + 1.0f);
        const float sg = __builtin_amdgcn_rcpf(1.0f + __expf(-gp[r]));
        bz[r] = to_bf16(tf * sg);
        bz[r + 4] = 0;
    }
    return __builtin_amdgcn_mfma_f32_16x16x32_bf16(ar, bz, cr, 0, 0, 0);
}

// ---------------- fused multi-layer segment kernel ----------------------------
// Block owns T = blockDim.x output positions; computes first layer at
// Wp = T + H positions (inputs from GLOBAL -> no halo cost on layer 1),
// then runs remaining layers entirely in LDS (halo H = sum of their dils).
// LDS l <-> sequence pos n = n0 - H + l.  Positions with n<0 or l<deficit
// hold garbage that clean outputs provably never read (taps of clean pos
// stay clean; causal zero handled by n-d<0 check).
struct SegCfg { int d[6]; int nl; int jbase; int H; int l0; };

__global__ __launch_bounds__(512) void fused_k(
    const short* __restrict__ src, const float* __restrict__ x,
    const float* __restrict__ W0, const float* __restrict__ b0,
    short* __restrict__ dst, const short* __restrict__ pk,
    const float* __restrict__ bfA, const float* __restrict__ bgA,
    const float* __restrict__ brA, SegCfg cfg)
{
    __shared__ short ldsA[1024 * NC];
    __shared__ short ldsB[1024 * NC];

    const int T = blockDim.x;
    const int Wp = T + cfg.H;          // multiple of 16 by construction
    const int ntile = Wp >> 4;
    const int t = threadIdx.x, lane = t & 63, wv = t >> 6, nw = blockDim.x >> 6;
    const int h = lane >> 4, i16 = lane & 15;
    const int tap = h >> 1, c0 = (h & 1) * 8;
    const int pbase = blockIdx.x * T;
    const int bb = pbase >> 14;
    const int n0 = pbase & (NN - 1);

    const float* xrow = x + (size_t)bb * NN;
    const short* srow = src + (size_t)bb * NN * NC;

    // ---- phase 0: first gated layer, inputs from global ----
    {
        const int d = cfg.d[0];
        const int j = cfg.jbase;
        const bf16x8 af = *(const bf16x8*)(pk + OFF_WF + j * 512 + lane * 8);
        const bf16x8 ag = *(const bf16x8*)(pk + OFF_WG + j * 512 + lane * 8);
        const bf16x8 ar = *(const bf16x8*)(pk + OFF_WR + j * 512 + lane * 8);
        const f4 v1 = *(const f4*)(bfA + j * 16 + h * 4);
        const f4 v2 = *(const f4*)(bgA + j * 16 + h * 4);
        const f4 v3 = *(const f4*)(brA + j * 16 + h * 4);
        const f32x4 cf = {v1.x, v1.y, v1.z, v1.w};
        const f32x4 cg = {v2.x, v2.y, v2.z, v2.w};
        const f32x4 cr = {v3.x, v3.y, v3.z, v3.w};

        for (int tau = wv; tau < ntile; tau += nw) {
            const int l = tau * 16 + i16;
            const int n = n0 - cfg.H + l;
            const int ns = tap ? n : n - d;   // tap0 = earlier sample
            bf16x8 bx;
            if (cfg.l0) {                      // build layer-0 output from x
                if (ns >= 0) {
                    const float xs = xrow[ns] * (1.0f / 32768.0f);
                    const float xm = (ns >= 1) ? xrow[ns - 1] * (1.0f / 32768.0f) : 0.0f;
#pragma unroll
                    for (int q = 0; q < 8; ++q) {
                        const int c = c0 + q;
                        bx[q] = to_bf16(xs + fmaf(W0[c * 2], xm,
                                        fmaf(W0[c * 2 + 1], xs, b0[c])));
                    }
                } else {
#pragma unroll
                    for (int q = 0; q < 8; ++q) bx[q] = 0;
                }
            } else {
                if (ns >= 0) {
                    bx = *(const bf16x8*)(srow + (size_t)ns * NC + c0);
                } else {
#pragma unroll
                    for (int q = 0; q < 8; ++q) bx[q] = 0;
                }
            }
            const f32x4 o = gated_core2(bx, af, ag, ar, cf, cg, cr);

            float o0, o1, o2, o3;              // residual input at (n, h*4..h*4+3)
            if (cfg.l0) {
                if (n >= 0) {
                    const float xs = xrow[n] * (1.0f / 32768.0f);
                    const float xm = (n >= 1) ? xrow[n - 1] * (1.0f / 32768.0f) : 0.0f;
                    const int c = h * 4;
                    o0 = xs + fmaf(W0[c * 2 + 0], xm, fmaf(W0[c * 2 + 1], xs, b0[c + 0]));
                    o1 = xs + fmaf(W0[c * 2 + 2], xm, fmaf(W0[c * 2 + 3], xs, b0[c + 1]));
                    o2 = xs + fmaf(W0[c * 2 + 4], xm, fmaf(W0[c * 2 + 5], xs, b0[c + 2]));
                    o3 = xs + fmaf(W0[c * 2 + 6], xm, fmaf(W0[c * 2 + 7], xs, b0[c + 3]));
                } else { o0 = o1 = o2 = o3 = 0.0f; }
            } else {
                if (n >= 0) {
                    const short4 ov = *(const short4*)(srow + (size_t)n * NC + h * 4);
                    o0 = from_bf16(ov.x); o1 = from_bf16(ov.y);
                    o2 = from_bf16(ov.z); o3 = from_bf16(ov.w);
                } else { o0 = o1 = o2 = o3 = 0.0f; }
            }
            const short4 w = make_short4(to_bf16(o0 + o[0]), to_bf16(o1 + o[1]),
                                         to_bf16(o2 + o[2]), to_bf16(o3 + o[3]));
            *(short4*)(ldsA + (size_t)l * NC + h * 4) = w;
        }
    }
    __syncthreads();

    // ---- layers 1..nl-1 entirely in LDS (ping-pong) ----
    int cur = 0;
#pragma unroll 1
    for (int s = 1; s < cfg.nl; ++s) {
        const int d = cfg.d[s];
        const int j = cfg.jbase + s;
        const bf16x8 af = *(const bf16x8*)(pk + OFF_WF + j * 512 + lane * 8);
        const bf16x8 ag = *(const bf16x8*)(pk + OFF_WG + j * 512 + lane * 8);
        const bf16x8 ar = *(const bf16x8*)(pk + OFF_WR + j * 512 + lane * 8);
        const f4 v1 = *(const f4*)(bfA + j * 16 + h * 4);
        const f4 v2 = *(const f4*)(bgA + j * 16 + h * 4);
        const f4 v3 = *(const f4*)(brA + j * 16 + h * 4);
        const f32x4 cf = {v1.x, v1.y, v1.z, v1.w};
        const f32x4 cg = {v2.x, v2.y, v2.z, v2.w};
        const f32x4 cr = {v3.x, v3.y, v3.z, v3.w};
        const short* rb = cur ? ldsB : ldsA;
        short* wb = cur ? ldsA : ldsB;

        for (int tau = wv; tau < ntile; tau += nw) {
            const int l = tau * 16 + i16;
            const int n = n0 - cfg.H + l;
            const int nt = tap ? n : n - d;
            int lt = tap ? l : l - d;
            if (lt < 0) lt = 0;                // garbage-region clamp (in-bounds)
            bf16x8 bx;
            if (nt >= 0) {
                bx = *(const bf16x8*)(rb + (size_t)lt * NC + c0);
            } else {
#pragma unroll
                for (int q = 0; q < 8; ++q) bx[q] = 0;
            }
            const f32x4 o = gated_core2(bx, af, ag, ar, cf, cg, cr);
            const short4 ov = *(const short4*)(rb + (size_t)l * NC + h * 4);
            const short4 w = make_short4(to_bf16(from_bf16(ov.x) + o[0]),
                                         to_bf16(from_bf16(ov.y) + o[1]),
                                         to_bf16(from_bf16(ov.z) + o[2]),
                                         to_bf16(from_bf16(ov.w) + o[3]));
            *(short4*)(wb + (size_t)l * NC + h * 4) = w;
        }
        __syncthreads();
        cur ^= 1;
    }

    // ---- writeback of the T owned positions ----
    const int otile = T >> 4;
    const short* rb = cur ? ldsB : ldsA;
    for (int tau = wv; tau < otile; tau += nw) {
        const int l = cfg.H + tau * 16 + i16;
        const int n = n0 + tau * 16 + i16;
        const short4 v = *(const short4*)(rb + (size_t)l * NC + h * 4);
        *(short4*)(dst + ((size_t)bb * NN + n) * NC + h * 4) = v;
    }
}

// ---------------- head via MFMA: skip->64->256->log_softmax, no LDS ----------
__global__ __launch_bounds__(256) void headm_k(
    const short* __restrict__ fin, const float* __restrict__ x,
    const int* __restrict__ lengths,
    const short* __restrict__ pka, const float* __restrict__ ba,
    const short* __restrict__ pko, const float* __restrict__ bo,
    float* __restrict__ out)
{
    const int t = threadIdx.x;
    const int lane = t & 63;
    const int wv = t >> 6;
    const int pos = blockIdx.x * 64 + wv * 16 + (lane & 15);
    const int h = lane >> 4;
    const int b = pos >> 14;
    const int n = pos & (NN - 1);

    // B fragment for Wa: sk = relu(fin - xs), channels k=h*8+j (real for h<2)
    bf16x8 bs;
    if (h < 2) {
        const float xs = x[pos] * (1.0f / 32768.0f);
        const bf16x8 v = *(const bf16x8*)(fin + (size_t)pos * NC + h * 8);
#pragma unroll
        for (int j = 0; j < 8; ++j)
            bs[j] = to_bf16(fmaxf(from_bf16(v[j]) - xs, 0.0f));
    } else {
#pragma unroll
        for (int j = 0; j < 8; ++j) bs[j] = 0;
    }

    // Wa GEMM: ra = relu(...), 16 values/lane, lane-local for Wo B-frags
    float ra[16];
#pragma unroll
    for (int mt = 0; mt < 4; ++mt) {
        const bf16x8 aa = *(const bf16x8*)(pka + (mt * 64 + lane) * 8);
        const f4 bav = *(const f4*)(ba + mt * 16 + h * 4);
        f32x4 c = {bav.x, bav.y, bav.z, bav.w};
        c = __builtin_amdgcn_mfma_f32_16x16x32_bf16(aa, bs, c, 0, 0, 0);
#pragma unroll
        for (int r = 0; r < 4; ++r) ra[mt * 4 + r] = fmaxf(c[r], 0.0f);
    }
    bf16x8 blo, bhi;
#pragma unroll
    for (int j = 0; j < 8; ++j) { blo[j] = to_bf16(ra[j]); bhi[j] = to_bf16(ra[8 + j]); }

    // Wo GEMM: 16 q-tiles x (2 MFMA, K=64); logits kept in VGPRs
    float lg[64];
#pragma unroll
    for (int qt = 0; qt < 16; ++qt) {
        const bf16x8 a0 = *(const bf16x8*)(pko + ((qt * 2 + 0) * 64 + lane) * 8);
        const bf16x8 a1 = *(const bf16x8*)(pko + ((qt * 2 + 1) * 64 + lane) * 8);
        const f4 bov = *(const f4*)(bo + qt * 16 + h * 4);
        f32x4 c = {bov.x, bov.y, bov.z, bov.w};
        c = __builtin_amdgcn_mfma_f32_16x16x32_bf16(a0, blo, c, 0, 0, 0);
        c = __builtin_amdgcn_mfma_f32_16x16x32_bf16(a1, bhi, c, 0, 0, 0);
#pragma unroll
        for (int r = 0; r < 4; ++r) lg[qt * 4 + r] = c[r];
    }

    // LSE: 256 logits/position live on lanes {i, i+16, i+32, i+48}
    float m = lg[0];
#pragma unroll
    for (int j = 1; j < 64; ++j) m = fmaxf(m, lg[j]);
    m = fmaxf(m, __shfl_xor(m, 16, 64));
    m = fmaxf(m, __shfl_xor(m, 32, 64));
    float s = 0.0f;
#pragma unroll
    for (int j = 0; j < 64; ++j) s += __expf(lg[j] - m);
    s += __shfl_xor(s, 16, 64);
    s += __shfl_xor(s, 32, 64);
    const float lse = m + __logf(s);
    const bool valid = n < lengths[b];

    // write: q = qt*16 + h*4 + r at out[b][q][n]
    float* ob = out + (size_t)b * 256 * NN + n;
#pragma unroll
    for (int qt = 0; qt < 16; ++qt)
#pragma unroll
        for (int r = 0; r < 4; ++r)
            ob[(size_t)(qt * 16 + h * 4 + r) * NN] = valid ? (lg[qt * 4 + r] - lse) : 0.0f;
}

extern "C" void kernel_launch(void* const* d_in, const int* in_sizes, int n_in,
                              void* d_out, int out_size, void* d_ws, size_t ws_size,
                              hipStream_t stream)
{
    const float* x       = (const float*)d_in[0];
    const int*   lengths = (const int*)d_in[1];
    const float* W0      = (const float*)d_in[2];
    const float* b0      = (const float*)d_in[3];
    const float* Wf      = (const float*)d_in[4];
    const float* bf      = (const float*)d_in[5];
    const float* Wg      = (const float*)d_in[6];
    const float* bg      = (const float*)d_in[7];
    const float* Wr      = (const float*)d_in[8];
    const float* br      = (const float*)d_in[9];
    const float* Wa      = (const float*)d_in[10];
    const float* ba      = (const float*)d_in[11];
    const float* Wo      = (const float*)d_in[12];
    const float* bo      = (const float*)d_in[13];
    float* out = (float*)d_out;

    short* bufA = (short*)d_ws;                         // (B,N,16) bf16, 4.2 MB
    short* bufB = bufA + (size_t)NPOSTOT * NC;          // ping-pong partner
    short* pk   = bufB + (size_t)NPOSTOT * NC;          // packed weight frags

    prepack_k<<<dim3((PK_TOT + 255) / 256), dim3(256), 0, stream>>>(
        Wf, Wg, Wr, Wa, Wo, pk);

    // Segment schedule: j = gated-layer index (0-based), d = 2^((j+1)%10).
    // halo H = sum of dils AFTER the first layer of each group (padded to x16).
    const SegCfg cfgs[9] = {
        {{2, 4, 8, 16, 32, 0}, 5, 0,  64,  1},   // K1: L0-fused + j0..j4
        {{64, 128, 0, 0, 0, 0}, 2, 5,  128, 0},  // K2
        {{256, 512, 0, 0, 0, 0}, 2, 7,  512, 0}, // K3 (T=512)
        {{1, 2, 4, 8, 16, 32},  6, 9,  64,  0},  // K4
        {{64, 128, 0, 0, 0, 0}, 2, 15, 128, 0},  // K5
        {{256, 512, 0, 0, 0, 0}, 2, 17, 512, 0}, // K6 (T=512)
        {{1, 2, 4, 8, 16, 32},  6, 19, 64,  0},  // K7
        {{64, 128, 0, 0, 0, 0}, 2, 25, 128, 0},  // K8
        {{256, 512, 0, 0, 0, 0}, 2, 27, 512, 0}, // K9 (T=512)
    };

    const short* cursrc = bufA;   // unused for K1 (l0 mode)
    short* bufs[2] = {bufA, bufB};
    int cur = 0;
    for (int k = 0; k < 9; ++k) {
        const int T = (cfgs[k].H == 512) ? 512 : 256;
        short* d = bufs[cur];
        fused_k<<<dim3(NPOSTOT / T), dim3(T), 0, stream>>>(
            cursrc, x, W0, b0, d, pk, bf, bg, br, cfgs[k]);
        cursrc = d;
        cur ^= 1;
    }

    // after 9 kernels the final stream is in bufA (K9 wrote bufs[0])
    headm_k<<<dim3(NPOSTOT / 64), dim3(256), 0, stream>>>(
        bufA, x, lengths, pk + OFF_WA, ba, pk + OFF_WO, bo, out);
}

// Round 6
// 151.149 us; speedup vs baseline: 7.8355x; 1.1516x over previous
//
#include <hip/hip_runtime.h>
#include <hip/hip_bf16.h>

#define NN 16384          // sequence length
#define NC 16             // layer channels
#define NPOSTOT 131072    // 8 * 16384
#define NLAY 29           // gated layers
#define TOUT 256          // output positions per block
#define LSTR 24           // LDS row stride in shorts (48 B -> bank-uniform)

typedef float4 f4;
typedef short bf16x8 __attribute__((ext_vector_type(8)));
typedef float f32x4 __attribute__((ext_vector_type(4)));

// prepack element offsets (in shorts)
#define OFF_WF 0
#define OFF_WG (NLAY * 512)
#define OFF_WR (2 * NLAY * 512)
#define OFF_WA (3 * NLAY * 512)
#define OFF_WO (3 * NLAY * 512 + 2048)
#define PK_TOT (OFF_WO + 16384)

static __device__ __forceinline__ short to_bf16(float f) {
    __hip_bfloat16 h = __float2bfloat16(f);   // RNE
    short s;
    __builtin_memcpy(&s, &h, 2);
    return s;
}
static __device__ __forceinline__ float from_bf16(short s) {
    unsigned int u = ((unsigned int)(unsigned short)s) << 16;
    float f;
    __builtin_memcpy(&f, &u, 4);
    return f;
}

// ---------------- weight prepack into MFMA A-fragments (bf16) -----------------
// Slot-consistency: A and B packed with the same (h=lane>>4, j)->k bijection.
//  conv (K=32):  k = h*8+j ; tap = k>>4, c = k&15           (B from memory)
//  1x1  (K=32):  j<4 -> k = h*4+j (=channel), j>=4 -> zero  (B = conv output)
//  Wa   (K=32):  k = h*8+j, real for k<16 (c=k), else zero  (B from memory)
//  Wo   (K=64):  half hf, k = hf*32 + (j>>2)*16 + h*4 + (j&3)  (B = Wa output)
__global__ __launch_bounds__(256) void prepack_k(
    const float* __restrict__ Wf, const float* __restrict__ Wg,
    const float* __restrict__ Wr, const float* __restrict__ Wa,
    const float* __restrict__ Wo, short* __restrict__ pk)
{
    const int i = blockIdx.x * 256 + threadIdx.x;
    if (i >= PK_TOT) return;
    float val;
    if (i < OFF_WG) {                               // Wf frags
        const int j = i >> 9, r = i & 511, l = r >> 3, j8 = r & 7;
        const int o = l & 15, h = l >> 4;
        const int k = h * 8 + j8, tap = k >> 4, c = k & 15;
        val = Wf[((j * 16 + o) * 16 + c) * 2 + tap];
    } else if (i < OFF_WA) {
        const int i2 = i - OFF_WG;
        if (i2 < NLAY * 512) {                      // Wg frags
            const int j = i2 >> 9, r = i2 & 511, l = r >> 3, j8 = r & 7;
            const int o = l & 15, h = l >> 4;
            const int k = h * 8 + j8, tap = k >> 4, c = k & 15;
            val = Wg[((j * 16 + o) * 16 + c) * 2 + tap];
        } else {                                    // Wr frags (half zero-padded)
            const int i3 = i2 - NLAY * 512;
            const int j = i3 >> 9, r = i3 & 511, l = r >> 3, j8 = r & 7;
            const int o = l & 15, h = l >> 4;
            val = (j8 < 4) ? Wr[j * 256 + o * 16 + h * 4 + j8] : 0.0f;
        }
    } else if (i < OFF_WO) {                        // Wa frags (4 m-tiles)
        const int i2 = i - OFF_WA;
        const int mt = i2 >> 9, r = i2 & 511, l = r >> 3, j8 = r & 7;
        const int og = mt * 16 + (l & 15), h = l >> 4;
        const int k = h * 8 + j8;
        val = (k < 16) ? Wa[og * 16 + k] : 0.0f;
    } else {                                        // Wo frags (16 q-tiles x 2 halves)
        const int i2 = i - OFF_WO;
        const int qt = i2 >> 10, hf = (i2 >> 9) & 1, r = i2 & 511;
        const int l = r >> 3, j8 = r & 7;
        const int q = qt * 16 + (l & 15), h = l >> 4;
        const int kg = hf * 32 + (j8 >> 2) * 16 + h * 4 + (j8 & 3);
        val = Wo[q * 64 + kg];
    }
    pk[i] = to_bf16(val);
}

// ---------------- gated MFMA core: 2 conv MFMA + merged act + 1x1 MFMA -------
static __device__ __forceinline__ f32x4 gated_core2(
    bf16x8 bx, bf16x8 af_, bf16x8 ag_, bf16x8 ar_,
    f32x4 cf, f32x4 cg, f32x4 cr)
{
    const f32x4 fp = __builtin_amdgcn_mfma_f32_16x16x32_bf16(af_, bx, cf, 0, 0, 0);
    const f32x4 gp = __builtin_amdgcn_mfma_f32_16x16x32_bf16(ag_, bx, cg, 0, 0, 0);

    bf16x8 bz;
#pragma unroll
    for (int r = 0; r < 4; ++r) {
        // z = tanh(f)*sigmoid(g) = (e^{2f}-1) / ((e^{2f}+1)(1+e^{-g}))
        const float ef = __expf(2.0f * fminf(fp[r], 43.0f));   // clamp: no inf
        const float eg = __expf(-gp[r]);
        const float den = fmaf(ef, eg, ef) + (eg + 1.0f);
        bz[r] = to_bf16((ef - 1.0f) * __builtin_amdgcn_rcpf(den));
        bz[r + 4] = 0;
    }
    return __builtin_amdgcn_mfma_f32_16x16x32_bf16(ar_, bz, cr, 0, 0, 0);
}

// ---------------- fused multi-layer segment kernel ----------------------------
// Block owns TOUT output positions + H halo; every wave owns exactly 2 16-pos
// tiles for the whole kernel, residual held in fp32 VGPRs; LDS carries only
// the bf16 tap stream (row stride 48 B, conflict-free).
struct SegCfg { int d[8]; int nl; int jbase; int H; int l0; };

__global__ __launch_bounds__(1024) void fused_k(
    const short* __restrict__ src, const float* __restrict__ x,
    const float* __restrict__ W0, const float* __restrict__ b0,
    short* __restrict__ dst, const short* __restrict__ pk,
    const float* __restrict__ bfA, const float* __restrict__ bgA,
    const float* __restrict__ brA, SegCfg cfg)
{
    extern __shared__ short lds[];
    const int H = cfg.H;
    const int Wp = TOUT + H;
    short* ldsA = lds;
    short* ldsB = lds + Wp * LSTR;

    const int t = threadIdx.x, lane = t & 63, wv = t >> 6;
    const int h = lane >> 4, i16 = lane & 15;
    const int tap = h >> 1, c0 = (h & 1) * 8;
    const int pbase = blockIdx.x * TOUT;
    const int bb = pbase >> 14, n0 = pbase & (NN - 1);
    const float* xrow = x + (size_t)bb * NN;
    const short* srow = src + (size_t)bb * NN * NC;

    const int l0r = wv * 32 + i16;     // this wave's tile-0 row in LDS coords
    const int l1r = l0r + 16;          // tile-1 row
    const int nA = n0 - H + l0r;       // sequence positions
    const int nB = nA + 16;

    f32x4 res0, res1;                  // fp32 residual, lives in VGPRs

    // ---- phase 0: first layer of the group, inputs from GLOBAL (no halo) ----
    {
        const int d = cfg.d[0];
        const int j = cfg.jbase;
        const bf16x8 af = *(const bf16x8*)(pk + OFF_WF + j * 512 + lane * 8);
        const bf16x8 ag = *(const bf16x8*)(pk + OFF_WG + j * 512 + lane * 8);
        const bf16x8 ar = *(const bf16x8*)(pk + OFF_WR + j * 512 + lane * 8);
        const f4 v1 = *(const f4*)(bfA + j * 16 + h * 4);
        const f4 v2 = *(const f4*)(bgA + j * 16 + h * 4);
        const f4 v3 = *(const f4*)(brA + j * 16 + h * 4);
        const f32x4 cf = {v1.x, v1.y, v1.z, v1.w};
        const f32x4 cg = {v2.x, v2.y, v2.z, v2.w};
        const f32x4 cr = {v3.x, v3.y, v3.z, v3.w};

        auto tile0 = [&](int l, int n, f32x4& res) {
            const int ns = tap ? n : n - d;
            bf16x8 bx = {0, 0, 0, 0, 0, 0, 0, 0};
            if (cfg.l0) {
                if (ns >= 0) {   // layer-0 output computed on the fly from x
                    const float xs = xrow[ns] * (1.0f / 32768.0f);
                    const float xm = (ns >= 1) ? xrow[ns - 1] * (1.0f / 32768.0f) : 0.0f;
#pragma unroll
                    for (int q2 = 0; q2 < 8; ++q2) {
                        const int c = c0 + q2;
                        bx[q2] = to_bf16(xs + fmaf(W0[c * 2], xm,
                                          fmaf(W0[c * 2 + 1], xs, b0[c])));
                    }
                }
            } else {
                if (ns >= 0) bx = *(const bf16x8*)(srow + (size_t)ns * NC + c0);
            }
            const f32x4 o = gated_core2(bx, af, ag, ar, cf, cg, cr);

            float r0, r1, r2, r3;        // residual input at (n, h*4..h*4+3)
            if (cfg.l0) {
                if (n >= 0) {
                    const float xs = xrow[n] * (1.0f / 32768.0f);
                    const float xm = (n >= 1) ? xrow[n - 1] * (1.0f / 32768.0f) : 0.0f;
                    const int c = h * 4;
                    r0 = xs + fmaf(W0[c * 2 + 0], xm, fmaf(W0[c * 2 + 1], xs, b0[c + 0]));
                    r1 = xs + fmaf(W0[c * 2 + 2], xm, fmaf(W0[c * 2 + 3], xs, b0[c + 1]));
                    r2 = xs + fmaf(W0[c * 2 + 4], xm, fmaf(W0[c * 2 + 5], xs, b0[c + 2]));
                    r3 = xs + fmaf(W0[c * 2 + 6], xm, fmaf(W0[c * 2 + 7], xs, b0[c + 3]));
                } else { r0 = r1 = r2 = r3 = 0.0f; }
            } else {
                if (n >= 0) {
                    const short4 ov = *(const short4*)(srow + (size_t)n * NC + h * 4);
                    r0 = from_bf16(ov.x); r1 = from_bf16(ov.y);
                    r2 = from_bf16(ov.z); r3 = from_bf16(ov.w);
                } else { r0 = r1 = r2 = r3 = 0.0f; }
            }
            res[0] = r0 + o[0]; res[1] = r1 + o[1];
            res[2] = r2 + o[2]; res[3] = r3 + o[3];
            *(short4*)(ldsA + l * LSTR + h * 4) =
                make_short4(to_bf16(res[0]), to_bf16(res[1]),
                            to_bf16(res[2]), to_bf16(res[3]));
        };
        tile0(l0r, nA, res0);
        tile0(l1r, nB, res1);
    }
    __syncthreads();

    // ---- layers 1..nl-1: taps from LDS, residual stays in registers ----
    int cur = 0;
    for (int s = 1; s < cfg.nl; ++s) {
        const int d = cfg.d[s];
        const int j = cfg.jbase + s;
        const bf16x8 af = *(const bf16x8*)(pk + OFF_WF + j * 512 + lane * 8);
        const bf16x8 ag = *(const bf16x8*)(pk + OFF_WG + j * 512 + lane * 8);
        const bf16x8 ar = *(const bf16x8*)(pk + OFF_WR + j * 512 + lane * 8);
        const f4 v1 = *(const f4*)(bfA + j * 16 + h * 4);
        const f4 v2 = *(const f4*)(bgA + j * 16 + h * 4);
        const f4 v3 = *(const f4*)(brA + j * 16 + h * 4);
        const f32x4 cf = {v1.x, v1.y, v1.z, v1.w};
        const f32x4 cg = {v2.x, v2.y, v2.z, v2.w};
        const f32x4 cr = {v3.x, v3.y, v3.z, v3.w};
        const short* rb = cur ? ldsB : ldsA;
        short* wb = cur ? ldsA : ldsB;

        auto tileL = [&](int l, int n, f32x4& res) {
            const int nt = tap ? n : n - d;
            int lt = tap ? l : l - d;
            if (lt < 0) lt = 0;          // garbage-region clamp (never read clean)
            bf16x8 bx = {0, 0, 0, 0, 0, 0, 0, 0};
            if (nt >= 0) bx = *(const bf16x8*)(rb + lt * LSTR + c0);
            const f32x4 o = gated_core2(bx, af, ag, ar, cf, cg, cr);
            res[0] += o[0]; res[1] += o[1]; res[2] += o[2]; res[3] += o[3];
            *(short4*)(wb + l * LSTR + h * 4) =
                make_short4(to_bf16(res[0]), to_bf16(res[1]),
                            to_bf16(res[2]), to_bf16(res[3]));
        };
        tileL(l0r, nA, res0);
        tileL(l1r, nB, res1);
        __syncthreads();
        cur ^= 1;
    }

    // ---- writeback of owned positions from registers ----
    if (l0r >= H) {
        *(short4*)(dst + ((size_t)bb * NN + nA) * NC + h * 4) =
            make_short4(to_bf16(res0[0]), to_bf16(res0[1]),
                        to_bf16(res0[2]), to_bf16(res0[3]));
    }
    if (l1r >= H) {
        *(short4*)(dst + ((size_t)bb * NN + nB) * NC + h * 4) =
            make_short4(to_bf16(res1[0]), to_bf16(res1[1]),
                        to_bf16(res1[2]), to_bf16(res1[3]));
    }
}

// ---------------- head via MFMA: skip->64->256->log_softmax, no LDS ----------
__global__ __launch_bounds__(256) void headm_k(
    const short* __restrict__ fin, const float* __restrict__ x,
    const int* __restrict__ lengths,
    const short* __restrict__ pka, const float* __restrict__ ba,
    const short* __restrict__ pko, const float* __restrict__ bo,
    float* __restrict__ out)
{
    const int t = threadIdx.x;
    const int lane = t & 63;
    const int wv = t >> 6;
    const int pos = blockIdx.x * 64 + wv * 16 + (lane & 15);
    const int h = lane >> 4;
    const int b = pos >> 14;
    const int n = pos & (NN - 1);

    // B fragment for Wa: sk = relu(fin - xs), channels k=h*8+j (real for h<2)
    bf16x8 bs;
    if (h < 2) {
        const float xs = x[pos] * (1.0f / 32768.0f);
        const bf16x8 v = *(const bf16x8*)(fin + (size_t)pos * NC + h * 8);
#pragma unroll
        for (int j = 0; j < 8; ++j)
            bs[j] = to_bf16(fmaxf(from_bf16(v[j]) - xs, 0.0f));
    } else {
#pragma unroll
        for (int j = 0; j < 8; ++j) bs[j] = 0;
    }

    // Wa GEMM: ra = relu(...), 16 values/lane, lane-local for Wo B-frags
    float ra[16];
#pragma unroll
    for (int mt = 0; mt < 4; ++mt) {
        const bf16x8 aa = *(const bf16x8*)(pka + (mt * 64 + lane) * 8);
        const f4 bav = *(const f4*)(ba + mt * 16 + h * 4);
        f32x4 c = {bav.x, bav.y, bav.z, bav.w};
        c = __builtin_amdgcn_mfma_f32_16x16x32_bf16(aa, bs, c, 0, 0, 0);
#pragma unroll
        for (int r = 0; r < 4; ++r) ra[mt * 4 + r] = fmaxf(c[r], 0.0f);
    }
    bf16x8 blo, bhi;
#pragma unroll
    for (int j = 0; j < 8; ++j) { blo[j] = to_bf16(ra[j]); bhi[j] = to_bf16(ra[8 + j]); }

    // Wo GEMM: 16 q-tiles x (2 MFMA, K=64); logits kept in VGPRs
    float lg[64];
#pragma unroll
    for (int qt = 0; qt < 16; ++qt) {
        const bf16x8 a0 = *(const bf16x8*)(pko + ((qt * 2 + 0) * 64 + lane) * 8);
        const bf16x8 a1 = *(const bf16x8*)(pko + ((qt * 2 + 1) * 64 + lane) * 8);
        const f4 bov = *(const f4*)(bo + qt * 16 + h * 4);
        f32x4 c = {bov.x, bov.y, bov.z, bov.w};
        c = __builtin_amdgcn_mfma_f32_16x16x32_bf16(a0, blo, c, 0, 0, 0);
        c = __builtin_amdgcn_mfma_f32_16x16x32_bf16(a1, bhi, c, 0, 0, 0);
#pragma unroll
        for (int r = 0; r < 4; ++r) lg[qt * 4 + r] = c[r];
    }

    // LSE: 256 logits/position live on lanes {i, i+16, i+32, i+48}
    float m = lg[0];
#pragma unroll
    for (int j = 1; j < 64; ++j) m = fmaxf(m, lg[j]);
    m = fmaxf(m, __shfl_xor(m, 16, 64));
    m = fmaxf(m, __shfl_xor(m, 32, 64));
    float s = 0.0f;
#pragma unroll
    for (int j = 0; j < 64; ++j) s += __expf(lg[j] - m);
    s += __shfl_xor(s, 16, 64);
    s += __shfl_xor(s, 32, 64);
    const float lse = m + __logf(s);
    const bool valid = n < lengths[b];

    // write: q = qt*16 + h*4 + r at out[b][q][n]
    float* ob = out + (size_t)b * 256 * NN + n;
#pragma unroll
    for (int qt = 0; qt < 16; ++qt)
#pragma unroll
        for (int r = 0; r < 4; ++r)
            ob[(size_t)(qt * 16 + h * 4 + r) * NN] = valid ? (lg[qt * 4 + r] - lse) : 0.0f;
}

extern "C" void kernel_launch(void* const* d_in, const int* in_sizes, int n_in,
                              void* d_out, int out_size, void* d_ws, size_t ws_size,
                              hipStream_t stream)
{
    const float* x       = (const float*)d_in[0];
    const int*   lengths = (const int*)d_in[1];
    const float* W0      = (const float*)d_in[2];
    const float* b0      = (const float*)d_in[3];
    const float* Wf      = (const float*)d_in[4];
    const float* bf      = (const float*)d_in[5];
    const float* Wg      = (const float*)d_in[6];
    const float* bg      = (const float*)d_in[7];
    const float* Wr      = (const float*)d_in[8];
    const float* br      = (const float*)d_in[9];
    const float* Wa      = (const float*)d_in[10];
    const float* ba      = (const float*)d_in[11];
    const float* Wo      = (const float*)d_in[12];
    const float* bo      = (const float*)d_in[13];
    float* out = (float*)d_out;

    short* bufA = (short*)d_ws;                         // (B,N,16) bf16, 4.2 MB
    short* bufB = bufA + (size_t)NPOSTOT * NC;
    short* pk   = bufB + (size_t)NPOSTOT * NC;          // packed weight frags

    prepack_k<<<dim3((PK_TOT + 255) / 256), dim3(256), 0, stream>>>(
        Wf, Wg, Wr, Wa, Wo, pk);

    // dils: j -> 2^((j+1)%10). Groups chosen so the big dilation opens a group
    // (first layer reads global -> free) and halo stays <= 256.
    const SegCfg cfgs[9] = {
        {{2, 4, 8, 16, 32, 64, 0, 0},  6, 0,  128, 1},  // G1: L0 + j0..j5
        {{128, 256, 0, 0, 0, 0, 0, 0}, 2, 6,  256, 0},  // G2: j6,j7
        {{512, 1, 2, 4, 8, 16, 32, 0}, 7, 8,  64,  0},  // G3: j8..j14
        {{64, 128, 0, 0, 0, 0, 0, 0},  2, 15, 128, 0},  // G4: j15,j16
        {{256, 0, 0, 0, 0, 0, 0, 0},   1, 17, 0,   0},  // G5: j17
        {{512, 1, 2, 4, 8, 16, 32, 0}, 7, 18, 64,  0},  // G6: j18..j24
        {{64, 128, 0, 0, 0, 0, 0, 0},  2, 25, 128, 0},  // G7: j25,j26
        {{256, 0, 0, 0, 0, 0, 0, 0},   1, 27, 0,   0},  // G8: j27
        {{512, 0, 0, 0, 0, 0, 0, 0},   1, 28, 0,   0},  // G9: j28
    };

    const short* cursrc = bufA;    // unused by G1 (l0 mode)
    short* bufs[2] = {bufA, bufB};
    int cur = 0;
    for (int k = 0; k < 9; ++k) {
        const SegCfg& c = cfgs[k];
        const int Wp = TOUT + c.H;
        const dim3 blk(Wp * 2);                        // (Wp/32) waves, 2 tiles/wave
        const size_t sh = (size_t)2 * Wp * LSTR * sizeof(short);
        short* d = bufs[cur];
        fused_k<<<dim3(NPOSTOT / TOUT), blk, sh, stream>>>(
            cursrc, x, W0, b0, d, pk, bf, bg, br, c);
        cursrc = d;
        cur ^= 1;
    }

    // G9 wrote bufA
    headm_k<<<dim3(NPOSTOT / 64), dim3(256), 0, stream>>>(
        bufA, x, lengths, pk + OFF_WA, ba, pk + OFF_WO, bo, out);
}